// Round 5
// baseline (96.505 us; speedup 1.0000x reference)
//
#include <hip/hip_runtime.h>

#define BATCH 8
#define CH 256

typedef float f4_t __attribute__((ext_vector_type(4)));

// ---------------------------------------------------------------------------
// Fused kernel 1 (r3-proven version): blocks [0,256) dot+pool on x0; blocks
// [256,512) two 3x3 convs on x2. Scalar dot loads (16 outstanding/lane is
// enough MLP; r4's float4 variant regressed). 512 threads/block.
// ---------------------------------------------------------------------------
__global__ __launch_bounds__(512)
void map_partial_kernel(const float* __restrict__ x0, const float* __restrict__ x2,
                        const float* __restrict__ cw0, const float* __restrict__ cb0,
                        const float* __restrict__ cw1, const float* __restrict__ cb1,
                        const float* __restrict__ ew0, const float* __restrict__ eb0,
                        const float* __restrict__ ew1, const float* __restrict__ eb1,
                        float* __restrict__ m1, float* __restrict__ m2,
                        float* __restrict__ c1, float* __restrict__ c2) {
    __shared__ float s1[512];
    __shared__ float s2[512];
    int t = threadIdx.x;

    if (blockIdx.x < 256) {
        // ---- dot + 4x4 pool on x0 [8,256,128,128] -> m1,m2 [8,32,32] ----
        int blk = blockIdx.x;
        int b   = blk >> 5;
        int p   = (blk & 31) * 512 + t;      // 4 image rows per block

        const float* xb = x0 + b * (CH * 16384) + p;
        float a1 = 0.f, a2 = 0.f;
#pragma unroll 16
        for (int c = 0; c < CH; ++c) {
            float v = xb[c * 16384];
            a1 += v * cw0[c];
            a2 += v * cw1[c];
        }
        s1[t] = a1; s2[t] = a2;
        __syncthreads();

        if (t < 32) {
            float t1 = 0.f, t2 = 0.f;
#pragma unroll
            for (int r = 0; r < 4; ++r)
#pragma unroll
                for (int j = 0; j < 4; ++j) {
                    t1 += s1[r * 128 + t * 4 + j];
                    t2 += s2[r * 128 + t * 4 + j];
                }
            int h = blk & 31;
            m1[b * 1024 + h * 32 + t] = fmaxf(t1 * 0.0625f + cb0[0], 0.f);
            m2[b * 1024 + h * 32 + t] = fmaxf(t2 * 0.0625f + cb1[0], 0.f);
        }
    } else {
        // ---- two 3x3 convs + relu on x2 [8,256,32,32] -> c1,c2 [8,32,32] ----
        int blk = blockIdx.x - 256;
        int y = blk & 31;
        int b = blk >> 5;
        int x  = t & 31;
        int cg = t >> 5;                      // 16 groups of 16 channels

        const float* xb = x2 + b * (CH * 1024);
        float a1 = 0.f, a2 = 0.f;

        for (int ci = 0; ci < 16; ++ci) {
            int c = cg * 16 + ci;
            const float* xc  = xb + c * 1024;
            const float* wc0 = ew0 + c * 9;
            const float* wc1 = ew1 + c * 9;
#pragma unroll
            for (int dy = -1; dy <= 1; ++dy) {
                int yy = y + dy;
                bool yok = (unsigned)yy < 32u;
#pragma unroll
                for (int dx = -1; dx <= 1; ++dx) {
                    int xx = x + dx;
                    bool ok = yok && ((unsigned)xx < 32u);
                    float v = ok ? xc[yy * 32 + xx] : 0.f;
                    int k = (dy + 1) * 3 + (dx + 1);
                    a1 += v * wc0[k];
                    a2 += v * wc1[k];
                }
            }
        }
        s1[t] = a1; s2[t] = a2;
        __syncthreads();

        if (t < 32) {
            float t1 = 0.f, t2 = 0.f;
#pragma unroll
            for (int g = 0; g < 16; ++g) { t1 += s1[g * 32 + x]; t2 += s2[g * 32 + x]; }
            c1[b * 1024 + y * 32 + x] = fmaxf(t1 + eb0[0], 0.f);
            c2[b * 1024 + y * 32 + x] = fmaxf(t2 + eb1[0], 0.f);
        }
    }
}

// ---------------------------------------------------------------------------
// Kernel 2 (finalize folded in): out = x + nearest(m1*mean(m2) + c1*mean(c2)).
// Each block serves exactly one (level, batch) — all per-batch level sizes are
// multiples of 256 f4 — so the block recomputes its batch means from
// m2/c2 (8 KB, L2-resident) at its head, then streams. NT stores keep the
// output from evicting inputs from L3.
// ---------------------------------------------------------------------------
template<int LOG2S>
__device__ __forceinline__ int map_coord(int p) {
    if constexpr (LOG2S >= 5) return p >> (LOG2S - 5);
    else                      return p << (5 - LOG2S);
}

template<int S, int LOG2S>
__device__ __forceinline__ void add_level(const f4_t* __restrict__ x,
                                          f4_t* __restrict__ out,
                                          const float* __restrict__ m1row_base,
                                          const float* __restrict__ c1row_base,
                                          float mm, float mc, int F) {
    constexpr int W4 = S / 4;
    int xq  = F & (W4 - 1);
    int row = F >> (LOG2S - 2);     // (b*256 + c)*S + y
    int y   = row & (S - 1);
    int my  = map_coord<LOG2S>(y);
    const float* m1row = m1row_base + my * 32;
    const float* c1row = c1row_base + my * 32;

    f4_t v = x[F];
    f4_t r;
    if constexpr (LOG2S == 7) {
        // 4x upsample: all 4 components share one map column (col = xq)
        float tm = m1row[xq] * mm + c1row[xq] * mc;
        r.x = v.x + tm; r.y = v.y + tm; r.z = v.z + tm; r.w = v.w + tm;
    } else if constexpr (LOG2S == 6) {
        // 2x upsample: pairs share a column
        float ta = m1row[2 * xq]     * mm + c1row[2 * xq]     * mc;
        float tb = m1row[2 * xq + 1] * mm + c1row[2 * xq + 1] * mc;
        r.x = v.x + ta; r.y = v.y + ta; r.z = v.z + tb; r.w = v.w + tb;
    } else if constexpr (LOG2S == 5) {
        // 1:1 — vector load of the map quad
        f4_t tm = ((const f4_t*)m1row)[xq] * mm + ((const f4_t*)c1row)[xq] * mc;
        r = v + tm;
    } else {
        int xp = xq * 4;
        float t0 = m1row[map_coord<LOG2S>(xp + 0)] * mm + c1row[map_coord<LOG2S>(xp + 0)] * mc;
        float t1 = m1row[map_coord<LOG2S>(xp + 1)] * mm + c1row[map_coord<LOG2S>(xp + 1)] * mc;
        float t2 = m1row[map_coord<LOG2S>(xp + 2)] * mm + c1row[map_coord<LOG2S>(xp + 2)] * mc;
        float t3 = m1row[map_coord<LOG2S>(xp + 3)] * mm + c1row[map_coord<LOG2S>(xp + 3)] * mc;
        r.x = v.x + t0; r.y = v.y + t1; r.z = v.z + t2; r.w = v.w + t3;
    }
    __builtin_nontemporal_store(r, out + F);
}

// float4 level boundaries (all multiples of 256)
#define E0 8388608
#define E1 10485760
#define E2 11010048
#define E3 11141120
#define E4 11173888

__global__ __launch_bounds__(256)
void add_all_kernel(const f4_t* __restrict__ x0, const f4_t* __restrict__ x1,
                    const f4_t* __restrict__ x2, const f4_t* __restrict__ x3,
                    const f4_t* __restrict__ x4, f4_t* __restrict__ out,
                    const float* __restrict__ m1, const float* __restrict__ m2,
                    const float* __restrict__ c1, const float* __restrict__ c2) {
    int t  = threadIdx.x;
    int g0 = blockIdx.x << 8;
    int g  = g0 + t;

    // block-uniform batch index (per-batch f4 counts: 2^20,2^18,2^16,2^14,2^12)
    int b;
    if (g0 < E0)      b = g0 >> 20;
    else if (g0 < E1) b = (g0 - E0) >> 18;
    else if (g0 < E2) b = (g0 - E1) >> 16;
    else if (g0 < E3) b = (g0 - E2) >> 14;
    else              b = (g0 - E3) >> 12;

    // per-block recompute of mean(m2[b]), mean(c2[b]) — 8 KB from L2
    const f4_t* m2f = (const f4_t*)m2 + b * 256;
    const f4_t* c2f = (const f4_t*)c2 + b * 256;
    f4_t v2 = m2f[t];
    f4_t w2 = c2f[t];
    float sm = v2.x + v2.y + v2.z + v2.w;
    float sc = w2.x + w2.y + w2.z + w2.w;
#pragma unroll
    for (int off = 32; off > 0; off >>= 1) {
        sm += __shfl_down(sm, off);
        sc += __shfl_down(sc, off);
    }
    __shared__ float rs[8];
    int wv = t >> 6, ln = t & 63;
    if (ln == 0) { rs[wv] = sm; rs[4 + wv] = sc; }
    __syncthreads();
    float mm = (rs[0] + rs[1] + rs[2] + rs[3]) * (1.f / 1024.f);
    float mc = (rs[4] + rs[5] + rs[6] + rs[7]) * (1.f / 1024.f);

    const float* m1b = m1 + b * 1024;
    const float* c1b = c1 + b * 1024;

    if (g < E0)      add_level<128, 7>(x0, out,      m1b, c1b, mm, mc, g);
    else if (g < E1) add_level< 64, 6>(x1, out + E0, m1b, c1b, mm, mc, g - E0);
    else if (g < E2) add_level< 32, 5>(x2, out + E1, m1b, c1b, mm, mc, g - E1);
    else if (g < E3) add_level< 16, 4>(x3, out + E2, m1b, c1b, mm, mc, g - E2);
    else             add_level<  8, 3>(x4, out + E3, m1b, c1b, mm, mc, g - E3);
}

// ---------------------------------------------------------------------------
extern "C" void kernel_launch(void* const* d_in, const int* in_sizes, int n_in,
                              void* d_out, int out_size, void* d_ws, size_t ws_size,
                              hipStream_t stream) {
    const float* x0 = (const float*)d_in[0];
    const float* x1 = (const float*)d_in[1];
    const float* x2 = (const float*)d_in[2];
    const float* x3 = (const float*)d_in[3];
    const float* x4 = (const float*)d_in[4];
    const float* com_w0 = (const float*)d_in[5];
    const float* com_b0 = (const float*)d_in[6];
    const float* com_w1 = (const float*)d_in[7];
    const float* com_b1 = (const float*)d_in[8];
    const float* en_w0  = (const float*)d_in[9];
    const float* en_b0  = (const float*)d_in[10];
    const float* en_w1  = (const float*)d_in[11];
    const float* en_b1  = (const float*)d_in[12];

    float* out = (float*)d_out;
    float* ws  = (float*)d_ws;
    float* m1   = ws;            // [8*1024] each
    float* m2   = ws + 8192;
    float* c1   = ws + 16384;
    float* c2   = ws + 24576;

    map_partial_kernel<<<512, 512, 0, stream>>>(
        x0, x2, com_w0, com_b0, com_w1, com_b1,
        en_w0, en_b0, en_w1, en_b1, m1, m2, c1, c2);

    add_all_kernel<<<E4 / 256, 256, 0, stream>>>(
        (const f4_t*)x0, (const f4_t*)x1, (const f4_t*)x2,
        (const f4_t*)x3, (const f4_t*)x4, (f4_t*)out, m1, m2, c1, c2);
}

// Round 6
// 90.174 us; speedup vs baseline: 1.0702x; 1.0702x over previous
//
#include <hip/hip_runtime.h>

#define BATCH 8
#define CH 256

typedef float f4_t __attribute__((ext_vector_type(4)));

// ---------------------------------------------------------------------------
// Fused kernel 1 (r3-proven): blocks [0,256) dot+pool on x0; blocks [256,512)
// two 3x3 convs on x2. Scalar dot loads (16 outstanding/lane suffices; the
// float4 variant of r4 regressed). 512 threads/block.
// ---------------------------------------------------------------------------
__global__ __launch_bounds__(512)
void map_partial_kernel(const float* __restrict__ x0, const float* __restrict__ x2,
                        const float* __restrict__ cw0, const float* __restrict__ cb0,
                        const float* __restrict__ cw1, const float* __restrict__ cb1,
                        const float* __restrict__ ew0, const float* __restrict__ eb0,
                        const float* __restrict__ ew1, const float* __restrict__ eb1,
                        float* __restrict__ m1, float* __restrict__ m2,
                        float* __restrict__ c1, float* __restrict__ c2) {
    __shared__ float s1[512];
    __shared__ float s2[512];
    int t = threadIdx.x;

    if (blockIdx.x < 256) {
        // ---- dot + 4x4 pool on x0 [8,256,128,128] -> m1,m2 [8,32,32] ----
        int blk = blockIdx.x;
        int b   = blk >> 5;
        int p   = (blk & 31) * 512 + t;      // 4 image rows per block

        const float* xb = x0 + b * (CH * 16384) + p;
        float a1 = 0.f, a2 = 0.f;
#pragma unroll 16
        for (int c = 0; c < CH; ++c) {
            float v = xb[c * 16384];
            a1 += v * cw0[c];
            a2 += v * cw1[c];
        }
        s1[t] = a1; s2[t] = a2;
        __syncthreads();

        if (t < 32) {
            float t1 = 0.f, t2 = 0.f;
#pragma unroll
            for (int r = 0; r < 4; ++r)
#pragma unroll
                for (int j = 0; j < 4; ++j) {
                    t1 += s1[r * 128 + t * 4 + j];
                    t2 += s2[r * 128 + t * 4 + j];
                }
            int h = blk & 31;
            m1[b * 1024 + h * 32 + t] = fmaxf(t1 * 0.0625f + cb0[0], 0.f);
            m2[b * 1024 + h * 32 + t] = fmaxf(t2 * 0.0625f + cb1[0], 0.f);
        }
    } else {
        // ---- two 3x3 convs + relu on x2 [8,256,32,32] -> c1,c2 [8,32,32] ----
        int blk = blockIdx.x - 256;
        int y = blk & 31;
        int b = blk >> 5;
        int x  = t & 31;
        int cg = t >> 5;                      // 16 groups of 16 channels

        const float* xb = x2 + b * (CH * 1024);
        float a1 = 0.f, a2 = 0.f;

        for (int ci = 0; ci < 16; ++ci) {
            int c = cg * 16 + ci;
            const float* xc  = xb + c * 1024;
            const float* wc0 = ew0 + c * 9;
            const float* wc1 = ew1 + c * 9;
#pragma unroll
            for (int dy = -1; dy <= 1; ++dy) {
                int yy = y + dy;
                bool yok = (unsigned)yy < 32u;
#pragma unroll
                for (int dx = -1; dx <= 1; ++dx) {
                    int xx = x + dx;
                    bool ok = yok && ((unsigned)xx < 32u);
                    float v = ok ? xc[yy * 32 + xx] : 0.f;
                    int k = (dy + 1) * 3 + (dx + 1);
                    a1 += v * wc0[k];
                    a2 += v * wc1[k];
                }
            }
        }
        s1[t] = a1; s2[t] = a2;
        __syncthreads();

        if (t < 32) {
            float t1 = 0.f, t2 = 0.f;
#pragma unroll
            for (int g = 0; g < 16; ++g) { t1 += s1[g * 32 + x]; t2 += s2[g * 32 + x]; }
            c1[b * 1024 + y * 32 + x] = fmaxf(t1 + eb0[0], 0.f);
            c2[b * 1024 + y * 32 + x] = fmaxf(t2 + eb1[0], 0.f);
        }
    }
}

// ---------------------------------------------------------------------------
// Kernel 2 (r3-proven): per-batch means of m2/c2 (wave shuffle reduce), then
// tmap = m1*mean(m2) + c1*mean(c2).  8 blocks x 256 threads, float4.
// ---------------------------------------------------------------------------
__global__ __launch_bounds__(256)
void finalize_map_kernel(const float4* __restrict__ m1, const float4* __restrict__ m2,
                         const float4* __restrict__ c1, const float4* __restrict__ c2,
                         float4* __restrict__ tmap) {
    int b = blockIdx.x;
    int t = threadIdx.x;
    float4 v2 = m2[b * 256 + t];
    float4 w2 = c2[b * 256 + t];
    float sm = v2.x + v2.y + v2.z + v2.w;
    float sc = w2.x + w2.y + w2.z + w2.w;
#pragma unroll
    for (int off = 32; off > 0; off >>= 1) {
        sm += __shfl_down(sm, off);
        sc += __shfl_down(sc, off);
    }
    __shared__ float rm[4];
    __shared__ float rc[4];
    int wave = t >> 6, lane = t & 63;
    if (lane == 0) { rm[wave] = sm; rc[wave] = sc; }
    __syncthreads();
    float mm = (rm[0] + rm[1] + rm[2] + rm[3]) * (1.f / 1024.f);
    float mc = (rc[0] + rc[1] + rc[2] + rc[3]) * (1.f / 1024.f);

    float4 a1 = m1[b * 256 + t];
    float4 a2 = c1[b * 256 + t];
    float4 r;
    r.x = a1.x * mm + a2.x * mc;
    r.y = a1.y * mm + a2.y * mc;
    r.z = a1.z * mm + a2.z * mc;
    r.w = a1.w * mm + a2.w * mc;
    tmap[b * 256 + t] = r;
}

// ---------------------------------------------------------------------------
// Kernel 3: fused out = x + nearest_resize(tmap) for ALL five levels.
// r3 structure (1 f4 per thread, NT stores) + NEW: per-level specialized map
// gather — level 0 all four output components share ONE map value (1 scalar
// load instead of 4), level 1 two, level 2 a single f4 load. Levels 3/4 keep
// the generic 4-load form (tiny).
// ---------------------------------------------------------------------------
template<int LOG2S>
__device__ __forceinline__ int map_coord(int p) {
    if constexpr (LOG2S >= 5) return p >> (LOG2S - 5);
    else                      return p << (5 - LOG2S);
}

template<int S, int LOG2S>
__device__ __forceinline__ void add_level(const f4_t* __restrict__ x,
                                          f4_t* __restrict__ out,
                                          const float* __restrict__ tmap, int F) {
    constexpr int W4 = S / 4;
    int xq  = F & (W4 - 1);
    int row = F >> (LOG2S - 2);     // (b*256 + c)*S + y
    int y   = row & (S - 1);
    int b   = (row >> LOG2S) >> 8;  // C = 256

    int my = map_coord<LOG2S>(y);
    const float* mrow = tmap + b * 1024 + my * 32;

    f4_t v = x[F];
    f4_t r;
    if constexpr (LOG2S == 7) {
        // 4x upsample in x: components 4q..4q+3 all map to column q
        float tm = mrow[xq];
        r.x = v.x + tm; r.y = v.y + tm; r.z = v.z + tm; r.w = v.w + tm;
    } else if constexpr (LOG2S == 6) {
        // 2x upsample: pairs share a column
        float ta = mrow[2 * xq];
        float tb = mrow[2 * xq + 1];
        r.x = v.x + ta; r.y = v.y + ta; r.z = v.z + tb; r.w = v.w + tb;
    } else if constexpr (LOG2S == 5) {
        // 1:1 — vector load of the map quad
        f4_t tm = ((const f4_t*)mrow)[xq];
        r = v + tm;
    } else {
        int xp = xq * 4;
        r.x = v.x + mrow[map_coord<LOG2S>(xp + 0)];
        r.y = v.y + mrow[map_coord<LOG2S>(xp + 1)];
        r.z = v.z + mrow[map_coord<LOG2S>(xp + 2)];
        r.w = v.w + mrow[map_coord<LOG2S>(xp + 3)];
    }
    __builtin_nontemporal_store(r, out + F);
}

// float4 level boundaries (all multiples of 256)
#define E0 8388608
#define E1 10485760
#define E2 11010048
#define E3 11141120
#define E4 11173888

__global__ __launch_bounds__(256)
void add_all_kernel(const f4_t* __restrict__ x0, const f4_t* __restrict__ x1,
                    const f4_t* __restrict__ x2, const f4_t* __restrict__ x3,
                    const f4_t* __restrict__ x4, f4_t* __restrict__ out,
                    const float* __restrict__ tmap) {
    int g = blockIdx.x * 256 + threadIdx.x;
    if (g < E0)      add_level<128, 7>(x0, out,      tmap, g);
    else if (g < E1) add_level< 64, 6>(x1, out + E0, tmap, g - E0);
    else if (g < E2) add_level< 32, 5>(x2, out + E1, tmap, g - E1);
    else if (g < E3) add_level< 16, 4>(x3, out + E2, tmap, g - E2);
    else             add_level<  8, 3>(x4, out + E3, tmap, g - E3);
}

// ---------------------------------------------------------------------------
extern "C" void kernel_launch(void* const* d_in, const int* in_sizes, int n_in,
                              void* d_out, int out_size, void* d_ws, size_t ws_size,
                              hipStream_t stream) {
    const float* x0 = (const float*)d_in[0];
    const float* x1 = (const float*)d_in[1];
    const float* x2 = (const float*)d_in[2];
    const float* x3 = (const float*)d_in[3];
    const float* x4 = (const float*)d_in[4];
    const float* com_w0 = (const float*)d_in[5];
    const float* com_b0 = (const float*)d_in[6];
    const float* com_w1 = (const float*)d_in[7];
    const float* com_b1 = (const float*)d_in[8];
    const float* en_w0  = (const float*)d_in[9];
    const float* en_b0  = (const float*)d_in[10];
    const float* en_w1  = (const float*)d_in[11];
    const float* en_b1  = (const float*)d_in[12];

    float* out = (float*)d_out;
    float* ws  = (float*)d_ws;
    float* m1   = ws;            // [8*1024] each
    float* m2   = ws + 8192;
    float* c1   = ws + 16384;
    float* c2   = ws + 24576;
    float* tmap = ws + 32768;

    map_partial_kernel<<<512, 512, 0, stream>>>(
        x0, x2, com_w0, com_b0, com_w1, com_b1,
        en_w0, en_b0, en_w1, en_b1, m1, m2, c1, c2);

    finalize_map_kernel<<<8, 256, 0, stream>>>(
        (const float4*)m1, (const float4*)m2,
        (const float4*)c1, (const float4*)c2, (float4*)tmap);

    add_all_kernel<<<E4 / 256, 256, 0, stream>>>(
        (const f4_t*)x0, (const f4_t*)x1, (const f4_t*)x2,
        (const f4_t*)x3, (const f4_t*)x4, (f4_t*)out, tmap);
}